// Round 8
// baseline (429.999 us; speedup 1.0000x reference)
//
#include <hip/hip_runtime.h>

// Soft differentiable rasterizer, forward only. Two-kernel structure.
// R7 -> R8:
//  * raster tiles 32x2 px (was 64x1): prim halo overlaps fewer tiles
//    ((L+32)/(L+64) ~ 0.6-0.75 survivor ratio), same wave = 64 px.
//  * setup cull reads per (row,slot): 36 scalar LDS -> 1 b32 + 6 b128 via
//    precomputed per-edge line form t = Q*gy + P, pos-edges-first ordering
//    (side flag becomes k < npos). Setup was LDS-inst-count bound (~22 us).
//  * per-row x-intervals tested against 4 x-quarters; row pairs OR'd ->
//    256 tiles/frame, lists stay 128 B.
// raster: coefficients via scalar cache (slot readfirstlane-uniform),
// 12 packed-fp32 sigmoid product, front-to-back T with wave exit at 2e-3.

#define HH 128
#define WW 128
#define NN 128
#define KK 12
#define STPB 1024
#define RTPB 256
#define STATE_SZ (NN * KK * 2 + NN) // 3200
#define CULL_U 15.0f
#define COEF_STRIDE 40              // floats per slot: A[12] B[12] C[12] gc[4]

typedef float f2 __attribute__((ext_vector_type(2)));

__global__ __launch_bounds__(STPB) void setup_kernel(
    const float* __restrict__ traj,
    const float* __restrict__ colors,
    const float* __restrict__ alpha,
    const float* __restrict__ zval,
    const void*  __restrict__ csg_raw,
    float* __restrict__ g_coef,         // [T][128][40]
    int* __restrict__ g_cnt,            // [T][256]
    unsigned char* __restrict__ g_list) // [T][256][128]
{
    __shared__ __align__(16) float s_coef[NN][COEF_STRIDE];       // 20.5 KB
    __shared__ __align__(16) float2 s_pq[NN][KK];                 // 12.3 KB
    __shared__ float s_state[STATE_SZ];                           // 12.8 KB
    __shared__ float s_orient[NN];
    __shared__ float s_z[NN];
    __shared__ int   s_slot2prim[NN];
    __shared__ int   s_npos[NN], s_nneg[NN];
    __shared__ unsigned long long s_qbits[HH][4][2];              // 8 KB
    __shared__ unsigned char s_list[4 * (HH / 2)][NN];            // 32 KB
    __shared__ int s_cnt[4 * (HH / 2)];
    __shared__ int s_mode;

    const int frame = blockIdx.x;
    const int tid   = threadIdx.x;
    const float* st = traj + (size_t)frame * STATE_SZ;

    // ---- stage + csg layout detect + counter init ----
    for (int i = tid; i < STATE_SZ; i += STPB) s_state[i] = st[i];
    if (tid < NN) { s_z[tid] = zval[tid]; s_npos[tid] = 0; s_nneg[tid] = 0; }
    if (tid == 0) {
        const unsigned char* b = (const unsigned char*)csg_raw;
        const unsigned int*  w = (const unsigned int*)csg_raw;
        int mode = 0; // int32
        bool words01 = true;
        for (int i = 0; i < 32; i++) if (w[i] > 1u) { words01 = false; break; }
        if (!words01) {
            bool bytes01 = true;
            for (int i = 0; i < 128; i++) if (b[i] > 1) { bytes01 = false; break; }
            mode = bytes01 ? 1 : 2;
        }
        s_mode = mode;
    }
    __syncthreads();

    // ---- per-prim: orient, g = alpha*sigmoid(alive), z-rank -> slot ----
    if (tid < NN) {
        const int n = tid;
        float area2 = 0.f;
        #pragma unroll
        for (int k = 0; k < KK; k++) {
            int k1 = (k + 1) % KK;
            float v0x = s_state[(n * KK + k)  * 2 + 0];
            float v0y = s_state[(n * KK + k)  * 2 + 1];
            float v1x = s_state[(n * KK + k1) * 2 + 0];
            float v1y = s_state[(n * KK + k1) * 2 + 1];
            area2 += v0x * v1y - v1x * v0y;
        }
        float orient = (area2 > 0.f) ? 1.f : ((area2 < 0.f) ? -1.f : 0.f);
        s_orient[n] = orient;

        float alive = s_state[NN * KK * 2 + n];
        float g = alpha[n] / (1.f + __expf(-alive));

        float zn = s_z[n];
        int rank = 0;
        for (int j = 0; j < NN; j++) {
            float zj = s_z[j];
            rank += (zj < zn || (zj == zn && j < n)) ? 1 : 0;
        }
        int slot = (NN - 1) - rank; // slot 0 = frontmost (largest z)
        s_slot2prim[slot] = n;

        int mode = s_mode;
        int sub;
        if (mode == 0)      sub = ((const int*)csg_raw)[n] != 0;
        else if (mode == 1) sub = ((const unsigned char*)csg_raw)[n] != 0;
        else                sub = ((const float*)csg_raw)[n] != 0.f;
        float cs = sub ? 0.f : 1.f;
        s_coef[slot][36] = g;
        s_coef[slot][37] = colors[n * 3 + 0] * cs;
        s_coef[slot][38] = colors[n * 3 + 1] * cs;
        s_coef[slot][39] = colors[n * 3 + 2] * cs;
    }
    __syncthreads();

    // ---- edge coefficients (slot-ordered SoA) ----
    const float QSCALE = 100.0f * 1.4426950408889634f;
    for (int idx = tid; idx < NN * KK; idx += STPB) {
        int slot = idx / KK;
        int k    = idx - slot * KK;
        int n    = s_slot2prim[slot];
        int k1   = (k + 1) % KK;
        float v0x = s_state[(n * KK + k)  * 2 + 0];
        float v0y = s_state[(n * KK + k)  * 2 + 1];
        float v1x = s_state[(n * KK + k1) * 2 + 0];
        float v1y = s_state[(n * KK + k1) * 2 + 1];
        float ex = v1x - v0x, ey = v1y - v0y;
        float q  = -s_orient[n] * QSCALE;
        s_coef[slot][0  + k] = q * ex;                      // A
        s_coef[slot][12 + k] = -q * ey;                     // B
        s_coef[slot][24 + k] = -q * (ex * v0y - ey * v0x);  // C
    }
    __syncthreads();

    // ---- line form per edge: x-constraint t(gy) = Q*gy + P ----
    // B>0: x <= t (stored as-is, +SLACK); B<=0: x >= t (stored negated:
    // -x <= -t, P = -P_raw + SLACK). Pos edges packed first (k < npos).
    const float SLACK = 0.01f;
    if (tid < NN * KK) {
        int slot = tid / KK;
        int k    = tid - slot * KK;
        float A = s_coef[slot][k];
        float B = s_coef[slot][12 + k];
        float C = s_coef[slot][24 + k];
        float rcpB = __builtin_amdgcn_rcpf(B);
        float Praw = (CULL_U - C) * rcpB;
        float Qraw = -A * rcpB;
        if (B > 0.f) {
            int i = atomicAdd(&s_npos[slot], 1);
            s_pq[slot][i] = make_float2(Qraw, Praw + SLACK);
        } else {
            int i = atomicAdd(&s_nneg[slot], 1);
            s_pq[slot][(KK - 1) - i] = make_float2(-Qraw, -Praw + SLACK);
        }
    }
    __syncthreads();

    // ---- joint interval cull; 4 x-quarter keep masks per row ----
    // wave covers one row (r const) x 64 slots (s = s0 + lane).
    const float GX_LO = 0.5f / WW;
    const float GX_HI = (WW - 0.5f) / WW;
    for (int j = 0; j < (HH * NN) / STPB; j++) {     // 16 iters
        int idx = j * STPB + tid;
        int r = idx >> 7, s = idx & (NN - 1);
        float gyr = (r + 0.5f) * (1.0f / HH);
        int npos = s_npos[s];
        const float4* pq4 = (const float4*)&s_pq[s][0];
        float y1 = 1e30f, y2 = 1e30f;
        #pragma unroll
        for (int h = 0; h < KK / 2; h++) {
            float4 v = pq4[h];                       // {Q,P,Q,P}
            int k0 = 2 * h, k1 = 2 * h + 1;
            float t0 = fmaf(v.x, gyr, v.y);
            float t1 = fmaf(v.z, gyr, v.w);
            bool p0 = k0 < npos, p1 = k1 < npos;
            y1 = fminf(y1, p0 ? t0 : 1e30f);
            y2 = fminf(y2, p0 ? 1e30f : t0);
            y1 = fminf(y1, p1 ? t1 : 1e30f);
            y2 = fminf(y2, p1 ? 1e30f : t1);
        }
        float xhi = fminf(y1, GX_HI);
        float xlo = fmaxf(-y2, GX_LO);
        bool ne = (xlo <= xhi);
        #pragma unroll
        for (int q = 0; q < 4; q++) {
            float qlo = (q * 32 + 0.5f) * (1.0f / WW);
            float qhi = (q * 32 + 31.5f) * (1.0f / WW);
            unsigned long long m = __ballot(ne && (xlo <= qhi) && (xhi >= qlo));
            if ((tid & 63) == 0) s_qbits[r][q][(s >= 64) ? 1 : 0] = m;
        }
    }
    __syncthreads();

    // ---- compaction: thread = tile (row-pair x x-quarter), slot-ascending ----
    if (tid < 4 * (HH / 2)) {
        int rp = tid >> 2, q = tid & 3;
        unsigned long long b0 = s_qbits[2 * rp][q][0] | s_qbits[2 * rp + 1][q][0];
        unsigned long long b1 = s_qbits[2 * rp][q][1] | s_qbits[2 * rp + 1][q][1];
        int n = 0;
        while (b0) { int k = __builtin_ctzll(b0); b0 &= b0 - 1; s_list[tid][n++] = (unsigned char)k; }
        while (b1) { int k = __builtin_ctzll(b1); b1 &= b1 - 1; s_list[tid][n++] = (unsigned char)(64 + k); }
        s_cnt[tid] = n;
    }
    __syncthreads();

    // ---- copy out ----
    {
        float* dstc = g_coef + (size_t)frame * (NN * COEF_STRIDE);
        const float* srcc = &s_coef[0][0];
        for (int i = tid; i < NN * COEF_STRIDE; i += STPB) dstc[i] = srcc[i];
        if (tid < 256) g_cnt[frame * 256 + tid] = s_cnt[tid];
        unsigned int* dstl = (unsigned int*)(g_list + (size_t)frame * (256 * NN));
        const unsigned int* srcl = (const unsigned int*)&s_list[0][0];
        for (int i = tid; i < (256 * NN) / 4; i += STPB) dstl[i] = srcl[i];
    }
}

struct F3 { float x, y, z; };

__global__ __launch_bounds__(RTPB) void raster_kernel(
    const float* __restrict__ g_coef,
    const int* __restrict__ g_cnt,
    const unsigned char* __restrict__ g_list,
    float* __restrict__ out)
{
    __shared__ unsigned char s_wlist[4][NN];

    const int tid   = threadIdx.x;
    const int wv    = __builtin_amdgcn_readfirstlane(tid >> 6);
    const int lane  = tid & 63;
    const int frame = blockIdx.y;
    const int tile  = blockIdx.x * 4 + wv;  // 0..255
    const int rp    = tile >> 2;            // row pair
    const int q     = tile & 3;             // x quarter

    // stage this wave's survivor list into its private LDS strip
    const unsigned char* lst = g_list + ((size_t)frame * 256 + tile) * NN;
    if (lane < NN / 4) {
        ((unsigned int*)&s_wlist[wv][0])[lane] = ((const unsigned int*)lst)[lane];
    }
    const int cnt = g_cnt[frame * 256 + tile]; // uniform -> s_load

    const int lx  = lane & 31, ly = lane >> 5;
    const int px  = q * 32 + lx;
    const int row = rp * 2 + ly;
    const float gy = (row + 0.5f) * (1.0f / HH);
    const float gx = (px  + 0.5f) * (1.0f / WW);
    const f2 gy2 = {gy, gy};
    const f2 gx2 = {gx, gx};
    const f2 lo2 = {-100.f, -100.f};

    const float* cfr = g_coef + (size_t)frame * (NN * COEF_STRIDE);

    float Tt = 1.f, rr = 0.f, gg = 0.f, bb = 0.f;
    for (int i = 0; i < cnt; i++) {
        int slot = __builtin_amdgcn_readfirstlane((int)s_wlist[wv][i]);
        const float* cf = cfr + slot * COEF_STRIDE; // uniform addr -> scalar loads
        const f2* A2 = (const f2*)(cf);
        const f2* B2 = (const f2*)(cf + 12);
        const f2* C2 = (const f2*)(cf + 24);

        f2 qv = {1.f, 1.f};
        #pragma unroll
        for (int j = 0; j < 6; j++) {
            f2 u = __builtin_elementwise_fma(B2[j], gx2,
                     __builtin_elementwise_fma(A2[j], gy2, C2[j]));
            u = __builtin_elementwise_max(u, lo2);   // exp2 underflow guard (inf*0=NaN)
            f2 e;
            e.x = __builtin_amdgcn_exp2f(u.x);
            e.y = __builtin_amdgcn_exp2f(u.y);
            qv = __builtin_elementwise_fma(qv, e, qv); // q *= 1 + 2^u
        }
        float cov = __builtin_amdgcn_rcpf(qv.x * qv.y);

        float a = cov * cf[36];
        float w = a * Tt;
        rr = fmaf(w, cf[37], rr);
        gg = fmaf(w, cf[38], gg);
        bb = fmaf(w, cf[39], bb);
        Tt = fmaf(-a, Tt, Tt);

        if (!__any(Tt > 2e-3f)) break;   // residual <= T < 2e-3
    }

    size_t o = ((size_t)frame * (HH * WW) + (size_t)row * WW + px) * 3;
    *(F3*)(out + o) = F3{rr, gg, bb};    // coalesced dwordx3 per row segment
}

extern "C" void kernel_launch(void* const* d_in, const int* in_sizes, int n_in,
                              void* d_out, int out_size, void* d_ws, size_t ws_size,
                              hipStream_t stream) {
    const float* traj   = (const float*)d_in[0];
    const float* colors = (const float*)d_in[1];
    const float* alpha  = (const float*)d_in[2];
    const float* zval   = (const float*)d_in[3];
    const void*  csg    = d_in[4];
    float* out = (float*)d_out;

    const int T = in_sizes[0] / STATE_SZ; // 192

    size_t coef_sz = (size_t)T * NN * COEF_STRIDE * sizeof(float); // 3.93 MB
    size_t cnt_sz  = (size_t)T * 256 * sizeof(int);                // 0.20 MB
    float* g_coef = (float*)d_ws;
    int*   g_cnt  = (int*)((char*)d_ws + coef_sz);
    unsigned char* g_list = (unsigned char*)d_ws + coef_sz + cnt_sz; // 6.29 MB

    setup_kernel<<<T, STPB, 0, stream>>>(traj, colors, alpha, zval, csg,
                                         g_coef, g_cnt, g_list);
    dim3 grid(256 / 4, T); // 64 x 192, wave = one 32x2 tile
    raster_kernel<<<grid, RTPB, 0, stream>>>(g_coef, g_cnt, g_list, out);
}

// Round 9
// 208.202 us; speedup vs baseline: 2.0653x; 2.0653x over previous
//
#include <hip/hip_runtime.h>

// Soft differentiable rasterizer, forward only. Two-kernel structure.
// R8 -> R9: BUGFIX. R8's line-form phase used `if (tid < NN*KK)` with
// STPB=1024 < NN*KK=1536 -> slots >= 86 had no constraints (npos=nneg=0)
// and were kept in EVERY tile (raster iters 46 -> 117, 178 -> 378 us).
// Now a strided loop. Also explicit B==0 -> no-constraint entry (safety).
// Design (from R8): 32x2 px tiles (halo shrink vs 64x1), setup cull via
// per-edge line form t = Q*gy + P read as float4 pairs, pos-first packing.
// raster: coefficients via scalar cache (slot readfirstlane-uniform),
// packed-fp32 sigmoid product, front-to-back T, wave exit at T < 2e-3.

#define HH 128
#define WW 128
#define NN 128
#define KK 12
#define STPB 1024
#define RTPB 256
#define STATE_SZ (NN * KK * 2 + NN) // 3200
#define CULL_U 15.0f
#define COEF_STRIDE 40              // floats per slot: A[12] B[12] C[12] gc[4]

typedef float f2 __attribute__((ext_vector_type(2)));

__global__ __launch_bounds__(STPB) void setup_kernel(
    const float* __restrict__ traj,
    const float* __restrict__ colors,
    const float* __restrict__ alpha,
    const float* __restrict__ zval,
    const void*  __restrict__ csg_raw,
    float* __restrict__ g_coef,         // [T][128][40]
    int* __restrict__ g_cnt,            // [T][256]
    unsigned char* __restrict__ g_list) // [T][256][128]
{
    __shared__ __align__(16) float s_coef[NN][COEF_STRIDE];       // 20.5 KB
    __shared__ __align__(16) float2 s_pq[NN][KK];                 // 12.3 KB
    __shared__ float s_state[STATE_SZ];                           // 12.8 KB
    __shared__ float s_orient[NN];
    __shared__ float s_z[NN];
    __shared__ int   s_slot2prim[NN];
    __shared__ int   s_npos[NN], s_nneg[NN];
    __shared__ unsigned long long s_qbits[HH][4][2];              // 8 KB
    __shared__ unsigned char s_list[4 * (HH / 2)][NN];            // 32 KB
    __shared__ int s_cnt[4 * (HH / 2)];
    __shared__ int s_mode;

    const int frame = blockIdx.x;
    const int tid   = threadIdx.x;
    const float* st = traj + (size_t)frame * STATE_SZ;

    // ---- stage + csg layout detect + counter init ----
    for (int i = tid; i < STATE_SZ; i += STPB) s_state[i] = st[i];
    if (tid < NN) { s_z[tid] = zval[tid]; s_npos[tid] = 0; s_nneg[tid] = 0; }
    if (tid == 0) {
        const unsigned char* b = (const unsigned char*)csg_raw;
        const unsigned int*  w = (const unsigned int*)csg_raw;
        int mode = 0; // int32
        bool words01 = true;
        for (int i = 0; i < 32; i++) if (w[i] > 1u) { words01 = false; break; }
        if (!words01) {
            bool bytes01 = true;
            for (int i = 0; i < 128; i++) if (b[i] > 1) { bytes01 = false; break; }
            mode = bytes01 ? 1 : 2;
        }
        s_mode = mode;
    }
    __syncthreads();

    // ---- per-prim: orient, g = alpha*sigmoid(alive), z-rank -> slot ----
    if (tid < NN) {
        const int n = tid;
        float area2 = 0.f;
        #pragma unroll
        for (int k = 0; k < KK; k++) {
            int k1 = (k + 1) % KK;
            float v0x = s_state[(n * KK + k)  * 2 + 0];
            float v0y = s_state[(n * KK + k)  * 2 + 1];
            float v1x = s_state[(n * KK + k1) * 2 + 0];
            float v1y = s_state[(n * KK + k1) * 2 + 1];
            area2 += v0x * v1y - v1x * v0y;
        }
        float orient = (area2 > 0.f) ? 1.f : ((area2 < 0.f) ? -1.f : 0.f);
        s_orient[n] = orient;

        float alive = s_state[NN * KK * 2 + n];
        float g = alpha[n] / (1.f + __expf(-alive));

        float zn = s_z[n];
        int rank = 0;
        for (int j = 0; j < NN; j++) {
            float zj = s_z[j];
            rank += (zj < zn || (zj == zn && j < n)) ? 1 : 0;
        }
        int slot = (NN - 1) - rank; // slot 0 = frontmost (largest z)
        s_slot2prim[slot] = n;

        int mode = s_mode;
        int sub;
        if (mode == 0)      sub = ((const int*)csg_raw)[n] != 0;
        else if (mode == 1) sub = ((const unsigned char*)csg_raw)[n] != 0;
        else                sub = ((const float*)csg_raw)[n] != 0.f;
        float cs = sub ? 0.f : 1.f;
        s_coef[slot][36] = g;
        s_coef[slot][37] = colors[n * 3 + 0] * cs;
        s_coef[slot][38] = colors[n * 3 + 1] * cs;
        s_coef[slot][39] = colors[n * 3 + 2] * cs;
    }
    __syncthreads();

    // ---- edge coefficients (slot-ordered SoA) ----
    const float QSCALE = 100.0f * 1.4426950408889634f;
    for (int idx = tid; idx < NN * KK; idx += STPB) {
        int slot = idx / KK;
        int k    = idx - slot * KK;
        int n    = s_slot2prim[slot];
        int k1   = (k + 1) % KK;
        float v0x = s_state[(n * KK + k)  * 2 + 0];
        float v0y = s_state[(n * KK + k)  * 2 + 1];
        float v1x = s_state[(n * KK + k1) * 2 + 0];
        float v1y = s_state[(n * KK + k1) * 2 + 1];
        float ex = v1x - v0x, ey = v1y - v0y;
        float q  = -s_orient[n] * QSCALE;
        s_coef[slot][0  + k] = q * ex;                      // A
        s_coef[slot][12 + k] = -q * ey;                     // B
        s_coef[slot][24 + k] = -q * (ex * v0y - ey * v0x);  // C
    }
    __syncthreads();

    // ---- line form per edge: x-constraint t(gy) = Q*gy + P ----
    // B>0: x <= t (+SLACK); B<0: x >= t (stored negated: -x <= -t, +SLACK);
    // B==0: no x-constraint -> neg-bucket entry with t' = +1e30 (never binds).
    // Pos edges packed first (k < npos). STRIDED LOOP (R8 bug: bare if).
    const float SLACK = 0.01f;
    for (int idx = tid; idx < NN * KK; idx += STPB) {
        int slot = idx / KK;
        int k    = idx - slot * KK;
        (void)k;
        float A = s_coef[slot][idx - slot * KK];
        float B = s_coef[slot][12 + (idx - slot * KK)];
        float C = s_coef[slot][24 + (idx - slot * KK)];
        float rcpB = __builtin_amdgcn_rcpf(B);
        float Praw = (CULL_U - C) * rcpB;
        float Qraw = -A * rcpB;
        if (B > 0.f) {
            int i = atomicAdd(&s_npos[slot], 1);
            s_pq[slot][i] = make_float2(Qraw, Praw + SLACK);
        } else if (B < 0.f) {
            int i = atomicAdd(&s_nneg[slot], 1);
            s_pq[slot][(KK - 1) - i] = make_float2(-Qraw, -Praw + SLACK);
        } else { // B == 0: x-independent edge; conservatively no constraint
            int i = atomicAdd(&s_nneg[slot], 1);
            s_pq[slot][(KK - 1) - i] = make_float2(0.f, 1e30f);
        }
    }
    __syncthreads();

    // ---- joint interval cull; 4 x-quarter keep masks per row ----
    // wave covers one row (r const) x 64 slots (s = s0 + lane).
    const float GX_LO = 0.5f / WW;
    const float GX_HI = (WW - 0.5f) / WW;
    for (int j = 0; j < (HH * NN) / STPB; j++) {     // 16 iters
        int idx = j * STPB + tid;
        int r = idx >> 7, s = idx & (NN - 1);
        float gyr = (r + 0.5f) * (1.0f / HH);
        int npos = s_npos[s];
        const float4* pq4 = (const float4*)&s_pq[s][0];
        float y1 = 1e30f, y2 = 1e30f;
        #pragma unroll
        for (int h = 0; h < KK / 2; h++) {
            float4 v = pq4[h];                       // {Q,P,Q,P}
            int k0 = 2 * h, k1 = 2 * h + 1;
            float t0 = fmaf(v.x, gyr, v.y);
            float t1 = fmaf(v.z, gyr, v.w);
            bool p0 = k0 < npos, p1 = k1 < npos;
            y1 = fminf(y1, p0 ? t0 : 1e30f);
            y2 = fminf(y2, p0 ? 1e30f : t0);
            y1 = fminf(y1, p1 ? t1 : 1e30f);
            y2 = fminf(y2, p1 ? 1e30f : t1);
        }
        float xhi = fminf(y1, GX_HI);
        float xlo = fmaxf(-y2, GX_LO);
        bool ne = (xlo <= xhi);
        #pragma unroll
        for (int q = 0; q < 4; q++) {
            float qlo = (q * 32 + 0.5f) * (1.0f / WW);
            float qhi = (q * 32 + 31.5f) * (1.0f / WW);
            unsigned long long m = __ballot(ne && (xlo <= qhi) && (xhi >= qlo));
            if ((tid & 63) == 0) s_qbits[r][q][(s >= 64) ? 1 : 0] = m;
        }
    }
    __syncthreads();

    // ---- compaction: thread = tile (row-pair x x-quarter), slot-ascending ----
    if (tid < 4 * (HH / 2)) {
        int rp = tid >> 2, q = tid & 3;
        unsigned long long b0 = s_qbits[2 * rp][q][0] | s_qbits[2 * rp + 1][q][0];
        unsigned long long b1 = s_qbits[2 * rp][q][1] | s_qbits[2 * rp + 1][q][1];
        int n = 0;
        while (b0) { int k = __builtin_ctzll(b0); b0 &= b0 - 1; s_list[tid][n++] = (unsigned char)k; }
        while (b1) { int k = __builtin_ctzll(b1); b1 &= b1 - 1; s_list[tid][n++] = (unsigned char)(64 + k); }
        s_cnt[tid] = n;
    }
    __syncthreads();

    // ---- copy out ----
    {
        float* dstc = g_coef + (size_t)frame * (NN * COEF_STRIDE);
        const float* srcc = &s_coef[0][0];
        for (int i = tid; i < NN * COEF_STRIDE; i += STPB) dstc[i] = srcc[i];
        if (tid < 256) g_cnt[frame * 256 + tid] = s_cnt[tid];
        unsigned int* dstl = (unsigned int*)(g_list + (size_t)frame * (256 * NN));
        const unsigned int* srcl = (const unsigned int*)&s_list[0][0];
        for (int i = tid; i < (256 * NN) / 4; i += STPB) dstl[i] = srcl[i];
    }
}

struct F3 { float x, y, z; };

__global__ __launch_bounds__(RTPB) void raster_kernel(
    const float* __restrict__ g_coef,
    const int* __restrict__ g_cnt,
    const unsigned char* __restrict__ g_list,
    float* __restrict__ out)
{
    __shared__ unsigned char s_wlist[4][NN];

    const int tid   = threadIdx.x;
    const int wv    = __builtin_amdgcn_readfirstlane(tid >> 6);
    const int lane  = tid & 63;
    const int frame = blockIdx.y;
    const int tile  = blockIdx.x * 4 + wv;  // 0..255
    const int rp    = tile >> 2;            // row pair
    const int q     = tile & 3;             // x quarter

    // stage this wave's survivor list into its private LDS strip
    const unsigned char* lst = g_list + ((size_t)frame * 256 + tile) * NN;
    if (lane < NN / 4) {
        ((unsigned int*)&s_wlist[wv][0])[lane] = ((const unsigned int*)lst)[lane];
    }
    const int cnt = g_cnt[frame * 256 + tile]; // uniform -> s_load

    const int lx  = lane & 31, ly = lane >> 5;
    const int px  = q * 32 + lx;
    const int row = rp * 2 + ly;
    const float gy = (row + 0.5f) * (1.0f / HH);
    const float gx = (px  + 0.5f) * (1.0f / WW);
    const f2 gy2 = {gy, gy};
    const f2 gx2 = {gx, gx};
    const f2 lo2 = {-100.f, -100.f};

    const float* cfr = g_coef + (size_t)frame * (NN * COEF_STRIDE);

    float Tt = 1.f, rr = 0.f, gg = 0.f, bb = 0.f;
    for (int i = 0; i < cnt; i++) {
        int slot = __builtin_amdgcn_readfirstlane((int)s_wlist[wv][i]);
        const float* cf = cfr + slot * COEF_STRIDE; // uniform addr -> scalar loads
        const f2* A2 = (const f2*)(cf);
        const f2* B2 = (const f2*)(cf + 12);
        const f2* C2 = (const f2*)(cf + 24);

        f2 qv = {1.f, 1.f};
        #pragma unroll
        for (int j = 0; j < 6; j++) {
            f2 u = __builtin_elementwise_fma(B2[j], gx2,
                     __builtin_elementwise_fma(A2[j], gy2, C2[j]));
            u = __builtin_elementwise_max(u, lo2);   // exp2 underflow guard (inf*0=NaN)
            f2 e;
            e.x = __builtin_amdgcn_exp2f(u.x);
            e.y = __builtin_amdgcn_exp2f(u.y);
            qv = __builtin_elementwise_fma(qv, e, qv); // q *= 1 + 2^u
        }
        float cov = __builtin_amdgcn_rcpf(qv.x * qv.y);

        float a = cov * cf[36];
        float w = a * Tt;
        rr = fmaf(w, cf[37], rr);
        gg = fmaf(w, cf[38], gg);
        bb = fmaf(w, cf[39], bb);
        Tt = fmaf(-a, Tt, Tt);

        if (!__any(Tt > 2e-3f)) break;   // residual <= T < 2e-3
    }

    size_t o = ((size_t)frame * (HH * WW) + (size_t)row * WW + px) * 3;
    *(F3*)(out + o) = F3{rr, gg, bb};    // coalesced dwordx3 per row segment
}

extern "C" void kernel_launch(void* const* d_in, const int* in_sizes, int n_in,
                              void* d_out, int out_size, void* d_ws, size_t ws_size,
                              hipStream_t stream) {
    const float* traj   = (const float*)d_in[0];
    const float* colors = (const float*)d_in[1];
    const float* alpha  = (const float*)d_in[2];
    const float* zval   = (const float*)d_in[3];
    const void*  csg    = d_in[4];
    float* out = (float*)d_out;

    const int T = in_sizes[0] / STATE_SZ; // 192

    size_t coef_sz = (size_t)T * NN * COEF_STRIDE * sizeof(float); // 3.93 MB
    size_t cnt_sz  = (size_t)T * 256 * sizeof(int);                // 0.20 MB
    float* g_coef = (float*)d_ws;
    int*   g_cnt  = (int*)((char*)d_ws + coef_sz);
    unsigned char* g_list = (unsigned char*)d_ws + coef_sz + cnt_sz; // 6.29 MB

    setup_kernel<<<T, STPB, 0, stream>>>(traj, colors, alpha, zval, csg,
                                         g_coef, g_cnt, g_list);
    dim3 grid(256 / 4, T); // 64 x 192, wave = one 32x2 tile
    raster_kernel<<<grid, RTPB, 0, stream>>>(g_coef, g_cnt, g_list, out);
}